// Round 1
// baseline (12473.333 us; speedup 1.0000x reference)
//
#include <hip/hip_runtime.h>
#include <math.h>

#define B_  2
#define S_  2048
#define H_  4096
#define NH_ 32
#define D_  128
#define M_  (B_*S_)   // 4096 rows (b*s)

// ---------------------------------------------------------------------------
// GEMM: C[M,N] = A[M,K] * Bt[N,K]^T   (Bt row-major N x K, i.e. weight (O,H))
// 64x64 tile, BK=16, 256 threads, 4x4 micro-tile per thread. fp32 baseline.
// ---------------------------------------------------------------------------
#define GT 64
#define GK 16

__global__ __launch_bounds__(256)
void gemm_bt_f32(const float* __restrict__ A, const float* __restrict__ Bt,
                 float* __restrict__ C, int M, int N, int K) {
  __shared__ float As[GK][GT + 4];   // +4 keeps 16B alignment, breaks pow2 stride
  __shared__ float Bs[GK][GT + 4];
  const int t  = threadIdx.x;
  const int tx = t & 15;
  const int ty = t >> 4;
  const int m0 = blockIdx.y * GT;
  const int n0 = blockIdx.x * GT;
  const int lm = t >> 2;          // 0..63  (row within tile)
  const int lk = (t & 3) << 2;    // 0,4,8,12 (k quad)

  float acc[4][4] = {{0.f}};

  const float* aptr = A + (size_t)(m0 + lm) * K + lk;
  const float* bptr = Bt + (size_t)(n0 + lm) * K + lk;

  for (int k0 = 0; k0 < K; k0 += GK) {
    float4 av = *(const float4*)(aptr + k0);
    float4 bv = *(const float4*)(bptr + k0);
    __syncthreads();   // previous iteration's reads done before overwrite
    As[lk + 0][lm] = av.x; As[lk + 1][lm] = av.y;
    As[lk + 2][lm] = av.z; As[lk + 3][lm] = av.w;
    Bs[lk + 0][lm] = bv.x; Bs[lk + 1][lm] = bv.y;
    Bs[lk + 2][lm] = bv.z; Bs[lk + 3][lm] = bv.w;
    __syncthreads();
#pragma unroll
    for (int kk = 0; kk < GK; ++kk) {
      float4 a4 = *(const float4*)&As[kk][ty << 2];
      float4 b4 = *(const float4*)&Bs[kk][tx << 2];
      acc[0][0] += a4.x * b4.x; acc[0][1] += a4.x * b4.y;
      acc[0][2] += a4.x * b4.z; acc[0][3] += a4.x * b4.w;
      acc[1][0] += a4.y * b4.x; acc[1][1] += a4.y * b4.y;
      acc[1][2] += a4.y * b4.z; acc[1][3] += a4.y * b4.w;
      acc[2][0] += a4.z * b4.x; acc[2][1] += a4.z * b4.y;
      acc[2][2] += a4.z * b4.z; acc[2][3] += a4.z * b4.w;
      acc[3][0] += a4.w * b4.x; acc[3][1] += a4.w * b4.y;
      acc[3][2] += a4.w * b4.z; acc[3][3] += a4.w * b4.w;
    }
  }
#pragma unroll
  for (int i = 0; i < 4; ++i) {
    float* cp = &C[(size_t)(m0 + (ty << 2) + i) * N + n0 + (tx << 2)];
    *(float4*)cp = make_float4(acc[i][0], acc[i][1], acc[i][2], acc[i][3]);
  }
}

// ---------------------------------------------------------------------------
// RoPE applied in-place to q and k. Layout (B,S,NH,D) flat = (B,S,H).
// table[pos][0:64]=sin, [64:128]=cos.
// ---------------------------------------------------------------------------
__global__ __launch_bounds__(256)
void rope_qk(float* __restrict__ q, float* __restrict__ k,
             const int* __restrict__ pos, const float* __restrict__ rt) {
  int idx = blockIdx.x * 256 + threadIdx.x;      // B*S*NH*64 threads
  int d  = idx & 63;
  int h  = (idx >> 6) & (NH_ - 1);
  int bs = idx >> 11;                            // b*S + s
  int p  = pos[bs];
  float sv = rt[p * D_ + d];
  float cv = rt[p * D_ + 64 + d];
  size_t base = ((size_t)bs * NH_ + h) * D_;
  float x1 = q[base + d], x2 = q[base + 64 + d];
  q[base + d]      = x1 * cv - x2 * sv;
  q[base + 64 + d] = x2 * cv + x1 * sv;
  x1 = k[base + d]; x2 = k[base + 64 + d];
  k[base + d]      = x1 * cv - x2 * sv;
  k[base + 64 + d] = x2 * cv + x1 * sv;
}

// ---------------------------------------------------------------------------
// Flash attention fwd (causal), fp32. Block: 32 q-rows, iterate 32-key tiles.
// 256 threads: 8 threads per q-row (wave-local groups -> shuffle reductions).
// Thread t: qi = t>>3, owns d = (t&7)*16 .. +15 of the O row.
// ---------------------------------------------------------------------------
#define FBQ 32
#define FBK 32
#define FDP (D_ + 4)   // 132: 16B-aligned rows, non-pow2 bank stride

__global__ __launch_bounds__(256)
void flash_fwd(const float* __restrict__ qb, const float* __restrict__ kb,
               const float* __restrict__ vb, float* __restrict__ ob) {
  const int q0 = blockIdx.x * FBQ;
  const int h  = blockIdx.y;
  const int b  = blockIdx.z;
  __shared__ float Qs[FBQ][FDP];
  __shared__ float Ks[FBK][FDP];
  __shared__ float Vs[FBK][FDP];
  __shared__ float Ps[FBQ][FBK + 4];

  const int t  = threadIdx.x;
  const int qi = t >> 3;          // 0..31
  const int l8 = t & 7;           // 0..7 within row group (wave-local)
  const int kc = l8 << 2;         // this thread's 4 score columns
  const int db = l8 << 4;         // this thread's 16 O columns

  // load Q tile (coalesced float4)
  for (int i = t; i < FBQ * D_ / 4; i += 256) {
    int r = i >> 5, d4 = (i & 31) << 2;
    *(float4*)&Qs[r][d4] =
        *(const float4*)&qb[(((size_t)b * S_ + q0 + r) * NH_ + h) * D_ + d4];
  }

  float oacc[16];
#pragma unroll
  for (int j = 0; j < 16; ++j) oacc[j] = 0.f;
  float m_run = -INFINITY, l_run = 0.f;
  const float scale = 0.088388347648318447f;   // 1/sqrt(128)
  const int qg = q0 + qi;
  const int kend = q0 + FBQ;

  for (int k0 = 0; k0 < kend; k0 += FBK) {
    __syncthreads();   // prior PV reads of Ks/Vs complete
    for (int i = t; i < FBK * D_ / 4; i += 256) {
      int r = i >> 5, d4 = (i & 31) << 2;
      size_t g = (((size_t)b * S_ + k0 + r) * NH_ + h) * D_ + d4;
      *(float4*)&Ks[r][d4] = *(const float4*)&kb[g];
      *(float4*)&Vs[r][d4] = *(const float4*)&vb[g];
    }
    __syncthreads();

    // ---- scores S[qi][kc..kc+3] = Q row . K rows ----
    float sc[4] = {0.f, 0.f, 0.f, 0.f};
#pragma unroll
    for (int d4 = 0; d4 < D_ / 4; ++d4) {
      float4 qv = *(const float4*)&Qs[qi][d4 << 2];
#pragma unroll
      for (int j = 0; j < 4; ++j) {
        float4 kv = *(const float4*)&Ks[kc + j][d4 << 2];
        sc[j] += qv.x * kv.x + qv.y * kv.y + qv.z * kv.z + qv.w * kv.w;
      }
    }
#pragma unroll
    for (int j = 0; j < 4; ++j)
      sc[j] = (k0 + kc + j <= qg) ? sc[j] * scale : -INFINITY;

    // ---- online softmax (8-lane wave-local row reduction) ----
    float tmax = fmaxf(fmaxf(sc[0], sc[1]), fmaxf(sc[2], sc[3]));
#pragma unroll
    for (int off = 1; off < 8; off <<= 1)
      tmax = fmaxf(tmax, __shfl_xor(tmax, off));
    float m_new = fmaxf(m_run, tmax);
    float alpha = __expf(m_run - m_new);
    float p0 = __expf(sc[0] - m_new);
    float p1 = __expf(sc[1] - m_new);
    float p2 = __expf(sc[2] - m_new);
    float p3 = __expf(sc[3] - m_new);
    float psum = p0 + p1 + p2 + p3;
#pragma unroll
    for (int off = 1; off < 8; off <<= 1)
      psum += __shfl_xor(psum, off);
    l_run = l_run * alpha + psum;
    m_run = m_new;
    *(float4*)&Ps[qi][kc] = make_float4(p0, p1, p2, p3);
#pragma unroll
    for (int j = 0; j < 16; ++j) oacc[j] *= alpha;
    __syncthreads();   // Ps visible (cheap safety; also orders Vs reuse)

    // ---- PV: O[qi][db..db+15] += P row . V rows ----
    float prow[FBK];
#pragma unroll
    for (int j4 = 0; j4 < FBK / 4; ++j4) {
      float4 pv = *(const float4*)&Ps[qi][j4 << 2];
      prow[j4 * 4 + 0] = pv.x; prow[j4 * 4 + 1] = pv.y;
      prow[j4 * 4 + 2] = pv.z; prow[j4 * 4 + 3] = pv.w;
    }
#pragma unroll
    for (int kj = 0; kj < FBK; ++kj) {
      float p = prow[kj];
      float4 v0 = *(const float4*)&Vs[kj][db + 0];
      float4 v1 = *(const float4*)&Vs[kj][db + 4];
      float4 v2 = *(const float4*)&Vs[kj][db + 8];
      float4 v3 = *(const float4*)&Vs[kj][db + 12];
      oacc[0]  += p * v0.x; oacc[1]  += p * v0.y;
      oacc[2]  += p * v0.z; oacc[3]  += p * v0.w;
      oacc[4]  += p * v1.x; oacc[5]  += p * v1.y;
      oacc[6]  += p * v1.z; oacc[7]  += p * v1.w;
      oacc[8]  += p * v2.x; oacc[9]  += p * v2.y;
      oacc[10] += p * v2.z; oacc[11] += p * v2.w;
      oacc[12] += p * v3.x; oacc[13] += p * v3.y;
      oacc[14] += p * v3.z; oacc[15] += p * v3.w;
    }
  }

  float inv_l = 1.0f / l_run;
  size_t obase = (((size_t)b * S_ + q0 + qi) * NH_ + h) * D_ + db;
#pragma unroll
  for (int j4 = 0; j4 < 4; ++j4) {
    *(float4*)&ob[obase + j4 * 4] =
        make_float4(oacc[j4 * 4 + 0] * inv_l, oacc[j4 * 4 + 1] * inv_l,
                    oacc[j4 * 4 + 2] * inv_l, oacc[j4 * 4 + 3] * inv_l);
  }
}

// ---------------------------------------------------------------------------
extern "C" void kernel_launch(void* const* d_in, const int* in_sizes, int n_in,
                              void* d_out, int out_size, void* d_ws, size_t ws_size,
                              hipStream_t stream) {
  const float* X   = (const float*)d_in[0];
  const int*   pid = (const int*)d_in[1];
  // d_in[2] attention_mask: analytically causal -- applied in-kernel, not read
  const float* Wq  = (const float*)d_in[3];
  const float* Wk  = (const float*)d_in[4];
  const float* Wv  = (const float*)d_in[5];
  const float* Wo  = (const float*)d_in[6];
  const float* rt  = (const float*)d_in[7];
  float* out = (float*)d_out;

  const size_t NE = (size_t)M_ * H_;   // 16,777,216 elems per buffer
  float* qb = (float*)d_ws;            // needs 4*NE*4 = 256 MiB of ws
  float* kb = qb + NE;
  float* vb = kb + NE;
  float* ab = vb + NE;

  dim3 gg(H_ / GT, M_ / GT);           // (64, 64)
  dim3 bk(256);
  gemm_bt_f32<<<gg, bk, 0, stream>>>(X, Wq, qb, M_, H_, H_);
  gemm_bt_f32<<<gg, bk, 0, stream>>>(X, Wk, kb, M_, H_, H_);
  gemm_bt_f32<<<gg, bk, 0, stream>>>(X, Wv, vb, M_, H_, H_);

  rope_qk<<<dim3((M_ * NH_ * 64) / 256), bk, 0, stream>>>(qb, kb, pid, rt);

  flash_fwd<<<dim3(S_ / FBQ, NH_, B_), bk, 0, stream>>>(qb, kb, vb, ab);

  gemm_bt_f32<<<gg, bk, 0, stream>>>(ab, Wo, out, M_, H_, H_);
}

// Round 2
// 4453.402 us; speedup vs baseline: 2.8009x; 2.8009x over previous
//
#include <hip/hip_runtime.h>
#include <math.h>

#define B_  2
#define S_  2048
#define H_  4096
#define NH_ 32
#define D_  128
#define M_  (B_*S_)   // 4096

typedef __attribute__((ext_vector_type(8))) __bf16 bf16x8;
typedef __attribute__((ext_vector_type(8))) unsigned short ushort8v;
typedef __attribute__((ext_vector_type(4))) float floatx4;

__device__ inline unsigned short f2bf(float f) {           // RNE fp32->bf16
  unsigned u = __float_as_uint(f);
  u += 0x7FFF + ((u >> 16) & 1);
  return (unsigned short)(u >> 16);
}
__device__ inline float bf2f(unsigned short s) {
  return __uint_as_float(((unsigned)s) << 16);
}

// ---------------------------------------------------------------------------
// fp32 -> bf16 cast, 8 elems/thread
// ---------------------------------------------------------------------------
__global__ __launch_bounds__(256)
void cast_f32_bf16(const float* __restrict__ s, unsigned short* __restrict__ d) {
  int i = (blockIdx.x * 256 + threadIdx.x) * 8;
  float4 a = *(const float4*)(s + i);
  float4 b = *(const float4*)(s + i + 4);
  ushort8v o;
  o[0] = f2bf(a.x); o[1] = f2bf(a.y); o[2] = f2bf(a.z); o[3] = f2bf(a.w);
  o[4] = f2bf(b.x); o[5] = f2bf(b.y); o[6] = f2bf(b.z); o[7] = f2bf(b.w);
  *(ushort8v*)(d + i) = o;
}

// ---------------------------------------------------------------------------
// bf16 MFMA GEMM (m97 structure): C[M,N] = A[M,K] * Bt[N,K]^T
// 128x128 block tile, BK=32, 256 thr (4 waves, 2x2), 4x4 MFMA tiles/wave.
// global_load_lds width-16 staging, single LDS buffer, 2-barrier K-loop.
// ---------------------------------------------------------------------------
#define TT 128
#define TK 32

__device__ inline void cstore(float* p, float v) { *p = v; }
__device__ inline void cstore(unsigned short* p, float v) { *p = f2bf(v); }

template <typename OT>
__global__ __launch_bounds__(256)
void gemm_bt_mfma(const unsigned short* __restrict__ A,
                  const unsigned short* __restrict__ Bt,
                  OT* __restrict__ C, int M, int N, int K) {
  __shared__ unsigned short As[TT * TK];   // 8 KB, row-major 128x32
  __shared__ unsigned short Bs[TT * TK];   // 8 KB
  const int t  = threadIdx.x;
  const int w  = t >> 6;          // wave 0..3
  const int l  = t & 63;
  const int wm = (w & 1) * 64;
  const int wn = (w >> 1) * 64;
  const int m0 = blockIdx.y * TT;
  const int n0 = blockIdx.x * TT;

  // staging map: wave w owns rows [w*32, w*32+32) of both tiles.
  // call covers 16 rows (64 lanes x 16 B): lane l -> row +(l>>2), bytes (l&3)*16
  const int srow = l >> 2;
  const int scol = (l & 3) * 8;                  // bf16 elems
  const unsigned short* agp = A  + (size_t)(m0 + w * 32 + srow) * K + scol;
  const unsigned short* bgp = Bt + (size_t)(n0 + w * 32 + srow) * K + scol;
  unsigned short* asd = As + w * 1024;           // seg base (elems), wave-uniform
  unsigned short* bsd = Bs + w * 1024;

  floatx4 acc[4][4] = {};
  const int lr = l & 15;
  const int kq = (l >> 4) * 8;

  for (int k0 = 0; k0 < K; k0 += TK) {
    __syncthreads();   // prior ds_reads done before overwrite
    __builtin_amdgcn_global_load_lds(
        (const __attribute__((address_space(1))) void*)(agp + k0),
        (__attribute__((address_space(3))) void*)(asd), 16, 0, 0);
    __builtin_amdgcn_global_load_lds(
        (const __attribute__((address_space(1))) void*)(agp + (size_t)16 * K + k0),
        (__attribute__((address_space(3))) void*)(asd + 512), 16, 0, 0);
    __builtin_amdgcn_global_load_lds(
        (const __attribute__((address_space(1))) void*)(bgp + k0),
        (__attribute__((address_space(3))) void*)(bsd), 16, 0, 0);
    __builtin_amdgcn_global_load_lds(
        (const __attribute__((address_space(1))) void*)(bgp + (size_t)16 * K + k0),
        (__attribute__((address_space(3))) void*)(bsd + 512), 16, 0, 0);
    __syncthreads();   // compiler drains vmcnt before s_barrier

    bf16x8 af[4], bfr[4];
#pragma unroll
    for (int i = 0; i < 4; ++i) {
      af[i]  = *(const bf16x8*)(As + (wm + i * 16 + lr) * TK + kq);
      bfr[i] = *(const bf16x8*)(Bs + (wn + i * 16 + lr) * TK + kq);
    }
#pragma unroll
    for (int mi = 0; mi < 4; ++mi)
#pragma unroll
      for (int ni = 0; ni < 4; ++ni)
        acc[mi][ni] = __builtin_amdgcn_mfma_f32_16x16x32_bf16(
            af[mi], bfr[ni], acc[mi][ni], 0, 0, 0);
  }

  // C/D: col = lane&15, row = (lane>>4)*4 + reg   [m89/m91 verified]
  const int rg = (l >> 4) * 4;
#pragma unroll
  for (int mi = 0; mi < 4; ++mi)
#pragma unroll
    for (int ni = 0; ni < 4; ++ni)
#pragma unroll
      for (int i = 0; i < 4; ++i) {
        size_t row = (size_t)m0 + wm + mi * 16 + rg + i;
        size_t col = (size_t)n0 + wn + ni * 16 + lr;
        cstore(&C[row * N + col], acc[mi][ni][i]);
      }
}

// ---------------------------------------------------------------------------
// RoPE in-place on bf16 q,k. Layout (B,S,NH,D).
// ---------------------------------------------------------------------------
__global__ __launch_bounds__(256)
void rope_qk(unsigned short* __restrict__ q, unsigned short* __restrict__ k,
             const int* __restrict__ pos, const float* __restrict__ rt) {
  int idx = blockIdx.x * 256 + threadIdx.x;      // B*S*NH*64 threads
  int d  = idx & 63;
  int h  = (idx >> 6) & (NH_ - 1);
  int bs = idx >> 11;
  int p  = pos[bs];
  float sv = rt[p * D_ + d];
  float cv = rt[p * D_ + 64 + d];
  size_t base = ((size_t)bs * NH_ + h) * D_;
  float x1 = bf2f(q[base + d]), x2 = bf2f(q[base + 64 + d]);
  q[base + d]      = f2bf(x1 * cv - x2 * sv);
  q[base + 64 + d] = f2bf(x2 * cv + x1 * sv);
  x1 = bf2f(k[base + d]); x2 = bf2f(k[base + 64 + d]);
  k[base + d]      = f2bf(x1 * cv - x2 * sv);
  k[base + 64 + d] = f2bf(x2 * cv + x1 * sv);
}

// ---------------------------------------------------------------------------
// Flash fwd (causal), fp32 compute, bf16 in/out.
// 32 q-rows/block, 32-key tiles, 256 thr; 8 thr per q-row (wave-local).
// Ks: unpadded, quad-swizzled (cq ^= row>>2) -> conflict-free QK reads.
// Vs: unpadded, PV ownership interleaved (quads l8, l8+8, l8+16, l8+24).
// ---------------------------------------------------------------------------
#define FBQ 32
#define FBK 32

__global__ __launch_bounds__(256)
void flash_fwd(const unsigned short* __restrict__ qb,
               const unsigned short* __restrict__ kb,
               const unsigned short* __restrict__ vb,
               unsigned short* __restrict__ ob) {
  const int q0 = blockIdx.x * FBQ;
  const int h  = blockIdx.y;
  const int b  = blockIdx.z;
  __shared__ float Qs[FBQ][132];       // +4 pad: conflict-free Q reads
  __shared__ float Ks[FBK * 128];      // swizzled
  __shared__ float Vs[FBK * 128];
  __shared__ float Ps[FBQ][36];

  const int t  = threadIdx.x;
  const int qi = t >> 3;
  const int l8 = t & 7;
  const int kc = l8 << 2;

  // ---- Q tile: bf16 -> fp32 LDS (2 passes x 8 elems) ----
  for (int p = 0; p < 2; ++p) {
    int i = t + p * 256;
    int r = i >> 4, e0 = (i & 15) << 3;
    ushort8v raw = *(const ushort8v*)&qb[(((size_t)b * S_ + q0 + r) * NH_ + h) * D_ + e0];
    float4 lo = make_float4(bf2f(raw[0]), bf2f(raw[1]), bf2f(raw[2]), bf2f(raw[3]));
    float4 hi = make_float4(bf2f(raw[4]), bf2f(raw[5]), bf2f(raw[6]), bf2f(raw[7]));
    *(float4*)&Qs[r][e0]     = lo;
    *(float4*)&Qs[r][e0 + 4] = hi;
  }

  float oacc[16];
#pragma unroll
  for (int j = 0; j < 16; ++j) oacc[j] = 0.f;
  float m_run = -INFINITY, l_run = 0.f;
  const float scale = 0.088388347648318447f;   // 1/sqrt(128)
  const int qg = q0 + qi;

  for (int k0 = 0; k0 < q0 + FBQ; k0 += FBK) {
    __syncthreads();
    for (int p = 0; p < 2; ++p) {
      int i = t + p * 256;
      int r = i >> 4, e0 = (i & 15) << 3;
      size_t g = (((size_t)b * S_ + k0 + r) * NH_ + h) * D_ + e0;
      ushort8v kr = *(const ushort8v*)&kb[g];
      ushort8v vr = *(const ushort8v*)&vb[g];
      int swz = (r >> 2) & 7;
      int cq  = e0 >> 2;
      *(float4*)&Ks[r * 128 + ((cq    ) ^ swz) * 4] =
          make_float4(bf2f(kr[0]), bf2f(kr[1]), bf2f(kr[2]), bf2f(kr[3]));
      *(float4*)&Ks[r * 128 + ((cq + 1) ^ swz) * 4] =
          make_float4(bf2f(kr[4]), bf2f(kr[5]), bf2f(kr[6]), bf2f(kr[7]));
      *(float4*)&Vs[r * 128 + e0] =
          make_float4(bf2f(vr[0]), bf2f(vr[1]), bf2f(vr[2]), bf2f(vr[3]));
      *(float4*)&Vs[r * 128 + e0 + 4] =
          make_float4(bf2f(vr[4]), bf2f(vr[5]), bf2f(vr[6]), bf2f(vr[7]));
    }
    __syncthreads();

    // ---- scores: rows kc..kc+3; swizzle const for these rows = l8 ----
    float sc[4] = {0.f, 0.f, 0.f, 0.f};
#pragma unroll
    for (int d4 = 0; d4 < 32; ++d4) {
      float4 qv = *(const float4*)&Qs[qi][d4 << 2];
#pragma unroll
      for (int j = 0; j < 4; ++j) {
        float4 kv = *(const float4*)&Ks[(kc + j) * 128 + ((d4 ^ l8) << 2)];
        sc[j] += qv.x * kv.x + qv.y * kv.y + qv.z * kv.z + qv.w * kv.w;
      }
    }
#pragma unroll
    for (int j = 0; j < 4; ++j)
      sc[j] = (k0 + kc + j <= qg) ? sc[j] * scale : -INFINITY;

    // ---- online softmax (8-lane reduction) ----
    float tmax = fmaxf(fmaxf(sc[0], sc[1]), fmaxf(sc[2], sc[3]));
#pragma unroll
    for (int off = 1; off < 8; off <<= 1)
      tmax = fmaxf(tmax, __shfl_xor(tmax, off));
    float m_new = fmaxf(m_run, tmax);
    float alpha = __expf(m_run - m_new);
    float p0 = __expf(sc[0] - m_new);
    float p1 = __expf(sc[1] - m_new);
    float p2 = __expf(sc[2] - m_new);
    float p3 = __expf(sc[3] - m_new);
    float psum = p0 + p1 + p2 + p3;
#pragma unroll
    for (int off = 1; off < 8; off <<= 1)
      psum += __shfl_xor(psum, off);
    l_run = l_run * alpha + psum;
    m_run = m_new;
    *(float4*)&Ps[qi][kc] = make_float4(p0, p1, p2, p3);
#pragma unroll
    for (int j = 0; j < 16; ++j) oacc[j] *= alpha;
    __syncthreads();

    // ---- PV: thread owns column quads {l8, l8+8, l8+16, l8+24} ----
    float prow[FBK];
#pragma unroll
    for (int j4 = 0; j4 < FBK / 4; ++j4) {
      float4 pv = *(const float4*)&Ps[qi][j4 << 2];
      prow[j4 * 4 + 0] = pv.x; prow[j4 * 4 + 1] = pv.y;
      prow[j4 * 4 + 2] = pv.z; prow[j4 * 4 + 3] = pv.w;
    }
#pragma unroll
    for (int kj = 0; kj < FBK; ++kj) {
      float p = prow[kj];
#pragma unroll
      for (int c = 0; c < 4; ++c) {
        float4 v = *(const float4*)&Vs[kj * 128 + ((l8 + c * 8) << 2)];
        oacc[c * 4 + 0] += p * v.x; oacc[c * 4 + 1] += p * v.y;
        oacc[c * 4 + 2] += p * v.z; oacc[c * 4 + 3] += p * v.w;
      }
    }
  }

  float inv_l = 1.0f / l_run;
  size_t obase = (((size_t)b * S_ + q0 + qi) * NH_ + h) * D_;
#pragma unroll
  for (int c = 0; c < 4; ++c) {
    size_t col = obase + ((l8 + c * 8) << 2);
    ob[col + 0] = f2bf(oacc[c * 4 + 0] * inv_l);
    ob[col + 1] = f2bf(oacc[c * 4 + 1] * inv_l);
    ob[col + 2] = f2bf(oacc[c * 4 + 2] * inv_l);
    ob[col + 3] = f2bf(oacc[c * 4 + 3] * inv_l);
  }
}

// ---------------------------------------------------------------------------
extern "C" void kernel_launch(void* const* d_in, const int* in_sizes, int n_in,
                              void* d_out, int out_size, void* d_ws, size_t ws_size,
                              hipStream_t stream) {
  const float* X   = (const float*)d_in[0];
  const int*   pid = (const int*)d_in[1];
  // d_in[2] attention_mask: analytically causal, applied in-kernel
  const float* Wq  = (const float*)d_in[3];
  const float* Wk  = (const float*)d_in[4];
  const float* Wv  = (const float*)d_in[5];
  const float* Wo  = (const float*)d_in[6];
  const float* rt  = (const float*)d_in[7];
  float* out = (float*)d_out;

  const size_t NE = (size_t)M_ * H_;             // 16.7M elems
  unsigned short* Xb  = (unsigned short*)d_ws;   // 8 x 33.5 MB = 256 MiB
  unsigned short* Wqb = Xb  + NE;
  unsigned short* Wkb = Wqb + NE;
  unsigned short* Wvb = Wkb + NE;
  unsigned short* Wob = Wvb + NE;
  unsigned short* qb  = Wob + NE;
  unsigned short* kb  = qb  + NE;
  unsigned short* vb  = kb  + NE;
  unsigned short* ab  = Xb;                      // alias: X dead after V proj

  dim3 bk(256);
  int cblocks = (int)(NE / 2048);                // 8192
  cast_f32_bf16<<<cblocks, bk, 0, stream>>>(X,  Xb);
  cast_f32_bf16<<<cblocks, bk, 0, stream>>>(Wq, Wqb);
  cast_f32_bf16<<<cblocks, bk, 0, stream>>>(Wk, Wkb);
  cast_f32_bf16<<<cblocks, bk, 0, stream>>>(Wv, Wvb);
  cast_f32_bf16<<<cblocks, bk, 0, stream>>>(Wo, Wob);

  dim3 gg(H_ / TT, M_ / TT);                     // 32 x 32
  gemm_bt_mfma<unsigned short><<<gg, bk, 0, stream>>>(Xb, Wqb, qb, M_, H_, H_);
  gemm_bt_mfma<unsigned short><<<gg, bk, 0, stream>>>(Xb, Wkb, kb, M_, H_, H_);
  gemm_bt_mfma<unsigned short><<<gg, bk, 0, stream>>>(Xb, Wvb, vb, M_, H_, H_);

  rope_qk<<<dim3((M_ * NH_ * 64) / 256), bk, 0, stream>>>(qb, kb, pid, rt);

  flash_fwd<<<dim3(S_ / FBQ, NH_, B_), bk, 0, stream>>>(qb, kb, vb, ab);

  gemm_bt_mfma<float><<<gg, bk, 0, stream>>>(ab, Wob, out, M_, H_, H_);
}